// Round 3
// baseline (245.935 us; speedup 1.0000x reference)
//
#include <hip/hip_runtime.h>
#include <hip/hip_fp16.h>
#include <math.h>

#define Bn 128
#define Nn 128
#define Ln 64
#define Pn 30
#define PG 10

// ws layout in 4-byte words:
#define TOFF  0        // tab:    [P][N*N] uint32 = half2{logsig(-l), l} : 491520 words
#define BOFF  491520   // Bpack:  [P][N][4] uint32 bitrows of (mask&Adj): 15360 words
#define VOFFW 506880   // validf: [P][N] float                          : 3840 words
#define ROFF  510720   // rec:    [B][P] float                          : 3840 words
#define KLOFF 514560   // KL mean (pre-divided by B)                    : 1 word
#define CNTOFF 514561  // completion counter                            : 1 word

// ---------------- K1: table build + bit-pack + KL + counter zero ----------------
__global__ __launch_bounds__(256) void k_prep(const float* __restrict__ mu,
                                              const float* __restrict__ logstd,
                                              const float* __restrict__ eps,
                                              const float* __restrict__ W,
                                              const int* __restrict__ Adj,
                                              const int* __restrict__ nm,
                                              float* __restrict__ ws) {
    int blk = blockIdx.x, t = threadIdx.x;
    if (blk < 192) {
        // table blocks: 64 uv-chunks x 3 p-groups of PG=10 graphs
        int chunk = blk & 63, pg = blk >> 6;
        __shared__ float zs[PG][Ln];
        for (int idx = t; idx < PG * Ln; idx += 256) {
            int g = pg * PG * Ln + idx;      // graph index == batch index for b < P
            zs[idx / Ln][idx % Ln] = mu[g] + eps[g] * __expf(logstd[g]);
        }
        __syncthreads();
        int uv = chunk * 256 + t;
        float acc[PG];
#pragma unroll
        for (int q = 0; q < PG; q++) acc[q] = 0.f;
        for (int k = 0; k < Ln; k++) {
            float w = W[k * (Nn * Nn) + uv];
#pragma unroll
            for (int q = 0; q < PG; q++) acc[q] = fmaf(zs[q][k], w, acc[q]);
        }
        uint32_t* tab = (uint32_t*)ws;
#pragma unroll
        for (int q = 0; q < PG; q++) {
            int p = pg * PG + q;
            float l = acc[q];
            float nl = -l;
            float lsneg = (nl < 0.f) ? (nl - log1pf(__expf(nl))) : (-log1pf(__expf(-nl)));
            __half2 h = __floats2half2_rn(lsneg, l);
            tab[p * (Nn * Nn) + uv] = *(uint32_t*)&h;
        }
    } else if (blk < 192 + Pn) {
        // bit-pack blocks: one per graph p. B = node_mask & Adj, 128 rows x 128 bits
        int p = blk - 192;
        __shared__ float val_s[Nn];
        if (t < Nn) {
            float v = (float)nm[p * Nn * Nn + t * Nn + t];  // diag = valid[t]
            val_s[t] = v;
            ws[VOFFW + p * Nn + t] = v;
        }
        __syncthreads();
        int sub = t >> 6, lane = t & 63;
        int ioff = sub >> 1, ch = sub & 1;       // 4 waves: 2 rows x 2 column-halves
        int j = ch * 64 + lane;
        uint32_t* Bp = (uint32_t*)ws + BOFF + p * Nn * 4;
        for (int ib = 0; ib < Nn; ib += 2) {
            int i = ib + ioff;
            bool pred = (Adj[p * Nn * Nn + i * Nn + j] != 0) &&
                        (val_s[i] != 0.f) && (val_s[j] != 0.f);
            unsigned long long m = __ballot(pred);
            if (lane == 0) {
                Bp[i * 4 + ch * 2]     = (uint32_t)m;
                Bp[i * 4 + ch * 2 + 1] = (uint32_t)(m >> 32);
            }
        }
    } else {
        // KL block: full KL sum over B*L elements, plus counter zero
        float kl = 0.f;
        for (int idx = t; idx < Bn * Ln; idx += 256) {
            float e = eps[idx], ls = logstd[idx];
            float z = mu[idx] + e * __expf(ls);
            kl += -0.5f * e * e - ls + 0.5f * z * z;   // 0.5*log(2pi) cancels
        }
        __shared__ float red[256];
        red[t] = kl;
        __syncthreads();
        for (int s = 128; s > 0; s >>= 1) {
            if (t < s) red[t] += red[t + s];
            __syncthreads();
        }
        if (t == 0) {
            ws[KLOFF] = red[0] * (1.0f / (float)Bn);
            ((uint32_t*)ws)[CNTOFF] = 0u;
        }
    }
}

// ---------------- K2: hot loop, 2 batches/block + fused finish ----------------
__global__ __launch_bounds__(256) void k_main(const int* __restrict__ perms,
                                              float* __restrict__ ws,
                                              float* __restrict__ out) {
    int p  = blockIdx.x >> 6;           // consecutive blocks share per-p data in L2
    int bb = blockIdx.x & 63;
    int b0 = bb * 2, b1 = b0 + 1;
    int t = threadIdx.x;

    __shared__ int      inv_s[2][Nn];
    __shared__ uint32_t B_s[Nn * 4];
    __shared__ float    valid_s[Nn];
    __shared__ float    redw[2][4];
    __shared__ int      flag;

    if (t < Nn) {
        inv_s[0][perms[(b0 * Pn + p) * Nn + t]] = t;
        valid_s[t] = ws[VOFFW + p * Nn + t];
    } else {
        inv_s[1][perms[(b1 * Pn + p) * Nn + (t - Nn)]] = t - Nn;
    }
    {
        const uint32_t* Bp = (const uint32_t*)ws + BOFF + p * Nn * 4;
        B_s[t]       = Bp[t];
        B_s[256 + t] = Bp[256 + t];
    }
    if (t == 0) flag = 0;
    __syncthreads();

    int lane = t & 63;
    int wid  = t >> 6;
    int v0 = 2 * lane, v1 = v0 + 1;

    // loop-invariant per (batch, slot) coordinates
    int   j00 = inv_s[0][v0], j01 = inv_s[0][v1];
    int   j10 = inv_s[1][v0], j11 = inv_s[1][v1];
    float wv00 = valid_s[j00], wv01 = valid_s[j01];
    float wv10 = valid_s[j10], wv11 = valid_s[j11];
    int   a00 = j00 >> 5, sh00 = j00 & 31;
    int   a01 = j01 >> 5, sh01 = j01 & 31;
    int   a10 = j10 >> 5, sh10 = j10 & 31;
    int   a11 = j11 >> 5, sh11 = j11 & 31;

    const uint2* tab2 = (const uint2*)((const uint32_t*)ws + p * (Nn * Nn));
    float acc0 = 0.f, acc1 = 0.f;

#pragma unroll 4
    for (int it = 0; it < 32; ++it) {
        int u = it * 4 + wid;                       // row: wave-uniform
        int   si0  = inv_s[0][u];                   // broadcast LDS reads
        int   si1  = inv_s[1][u];
        float swu0 = valid_s[si0];
        float swu1 = valid_s[si1];
        uint2 hw   = tab2[u * (Nn / 2) + lane];     // coalesced 8B/lane
        float2 f0  = __half22float2(*(__half2*)&hw.x);  // x=logsig(-l), y=l  @ v0
        float2 f1  = __half22float2(*(__half2*)&hw.y);  //                    @ v1

        // batch 0
        {
            float tmp = wv00 * f0.x;
            tmp = fmaf(wv01, f1.x, tmp);
            acc0 = fmaf(swu0, tmp, acc0);
            uint32_t r0 = B_s[si0 * 4 + a00];
            uint32_t r1 = B_s[si0 * 4 + a01];
            acc0 = fmaf((float)((r0 >> sh00) & 1u), f0.y, acc0);
            acc0 = fmaf((float)((r1 >> sh01) & 1u), f1.y, acc0);
        }
        // batch 1
        {
            float tmp = wv10 * f0.x;
            tmp = fmaf(wv11, f1.x, tmp);
            acc1 = fmaf(swu1, tmp, acc1);
            uint32_t r0 = B_s[si1 * 4 + a10];
            uint32_t r1 = B_s[si1 * 4 + a11];
            acc1 = fmaf((float)((r0 >> sh10) & 1u), f0.y, acc1);
            acc1 = fmaf((float)((r1 >> sh11) & 1u), f1.y, acc1);
        }
    }

    // wave reduce both accumulators
#pragma unroll
    for (int s = 32; s > 0; s >>= 1) {
        acc0 += __shfl_down(acc0, s, 64);
        acc1 += __shfl_down(acc1, s, 64);
    }
    if (lane == 0) { redw[0][wid] = acc0; redw[1][wid] = acc1; }
    __syncthreads();
    if (t < 2) {
        float r = redw[t][0] + redw[t][1] + redw[t][2] + redw[t][3];
        ws[ROFF + (b0 + t) * Pn + p] = r;
    }
    __threadfence();
    __syncthreads();
    if (t == 0) {
        uint32_t old = atomicAdd((uint32_t*)ws + CNTOFF, 1u);
        if (old == (uint32_t)(Pn * 64 - 1)) flag = 1;
    }
    __syncthreads();
    if (flag) {
        // last block: RE = sum_b max_p rec ; out = KLmean - RE
        __threadfence();
        __shared__ float red[128];
        if (t < 128) {
            float m = -INFINITY;
#pragma unroll
            for (int q = 0; q < Pn; q++) m = fmaxf(m, ws[ROFF + t * Pn + q]);
            red[t] = m;
        }
        __syncthreads();
        for (int s = 64; s > 0; s >>= 1) {
            if (t < s) red[t] += red[t + s];
            __syncthreads();
        }
        if (t == 0) out[0] = ws[KLOFF] - red[0];
    }
}

extern "C" void kernel_launch(void* const* d_in, const int* in_sizes, int n_in,
                              void* d_out, int out_size, void* d_ws, size_t ws_size,
                              hipStream_t stream) {
    const float* mu     = (const float*)d_in[0];
    const float* logstd = (const float*)d_in[1];
    const float* eps    = (const float*)d_in[2];
    const float* W      = (const float*)d_in[3];
    const int*   Adj    = (const int*)d_in[4];
    const int*   nm     = (const int*)d_in[5];
    const int*   perms  = (const int*)d_in[6];
    float* ws  = (float*)d_ws;
    float* out = (float*)d_out;

    hipLaunchKernelGGL(k_prep, dim3(192 + Pn + 1), dim3(256), 0, stream,
                       mu, logstd, eps, W, Adj, nm, ws);
    hipLaunchKernelGGL(k_main, dim3(Pn * 64),      dim3(256), 0, stream,
                       perms, ws, out);
}

// Round 4
// 124.172 us; speedup vs baseline: 1.9806x; 1.9806x over previous
//
#include <hip/hip_runtime.h>
#include <hip/hip_fp16.h>
#include <math.h>

#define Bn 128
#define Nn 128
#define Ln 64
#define Pn 30
#define PG 10

// ws layout in 4-byte words:
#define TOFF  0        // tab:    [P][N*N] uint32 = half2{logsig(-l), l} : 491520 words
#define BOFF  491520   // Bpack:  [P][N][4] uint32 bitrows of (mask&Adj): 15360 words
#define VOFFW 506880   // validf: [P][N] float                          : 3840 words
#define ROFF  510720   // rec:    [B][P] float                          : 3840 words

// ---------------- K1: table build (GEMM + logsig) + bit-pack ----------------
__global__ __launch_bounds__(256) void k_prep(const float* __restrict__ mu,
                                              const float* __restrict__ logstd,
                                              const float* __restrict__ eps,
                                              const float* __restrict__ W,
                                              const int* __restrict__ Adj,
                                              const int* __restrict__ nm,
                                              float* __restrict__ ws) {
    int blk = blockIdx.x, t = threadIdx.x;
    if (blk < 192) {
        // table blocks: 64 uv-chunks x 3 p-groups of PG=10 graphs
        int chunk = blk & 63, pg = blk >> 6;
        __shared__ float zs[PG][Ln];
        for (int idx = t; idx < PG * Ln; idx += 256) {
            int g = pg * PG * Ln + idx;      // graph index == batch index for b < P
            zs[idx / Ln][idx % Ln] = mu[g] + eps[g] * __expf(logstd[g]);
        }
        __syncthreads();
        int uv = chunk * 256 + t;
        float acc[PG];
#pragma unroll
        for (int q = 0; q < PG; q++) acc[q] = 0.f;
        for (int k = 0; k < Ln; k++) {
            float w = W[k * (Nn * Nn) + uv];
#pragma unroll
            for (int q = 0; q < PG; q++) acc[q] = fmaf(zs[q][k], w, acc[q]);
        }
        uint32_t* tab = (uint32_t*)ws;
#pragma unroll
        for (int q = 0; q < PG; q++) {
            int p = pg * PG + q;
            float l = acc[q];
            float nl = -l;
            float lsneg = (nl < 0.f) ? (nl - log1pf(__expf(nl))) : (-log1pf(__expf(-nl)));
            __half2 h = __floats2half2_rn(lsneg, l);
            tab[p * (Nn * Nn) + uv] = *(uint32_t*)&h;
        }
    } else {
        // bit-pack blocks: one per graph p. B = node_mask & Adj, 128 rows x 128 bits
        int p = blk - 192;
        __shared__ float val_s[Nn];
        if (t < Nn) {
            float v = (float)nm[p * Nn * Nn + t * Nn + t];  // diag = valid[t]
            val_s[t] = v;
            ws[VOFFW + p * Nn + t] = v;
        }
        __syncthreads();
        int sub = t >> 6, lane = t & 63;
        int ioff = sub >> 1, ch = sub & 1;       // 4 waves: 2 rows x 2 column-halves
        int j = ch * 64 + lane;
        uint32_t* Bp = (uint32_t*)ws + BOFF + p * Nn * 4;
        for (int ib = 0; ib < Nn; ib += 2) {
            int i = ib + ioff;
            bool pred = (Adj[p * Nn * Nn + i * Nn + j] != 0) &&
                        (val_s[i] != 0.f) && (val_s[j] != 0.f);
            unsigned long long m = __ballot(pred);
            if (lane == 0) {
                Bp[i * 4 + ch * 2]     = (uint32_t)m;
                Bp[i * 4 + ch * 2 + 1] = (uint32_t)(m >> 32);
            }
        }
    }
}

// ---------------- K2: hot loop, 2 batches/block ----------------
__global__ __launch_bounds__(256) void k_main(const int* __restrict__ perms,
                                              const float* __restrict__ ws,
                                              float* __restrict__ rec) {
    int p  = blockIdx.x >> 6;           // consecutive blocks share per-p data in L2
    int bb = blockIdx.x & 63;
    int b0 = bb * 2, b1 = b0 + 1;
    int t = threadIdx.x;

    __shared__ int      inv_s[2][Nn];
    __shared__ uint32_t B_s[Nn * 4];
    __shared__ float    valid_s[Nn];
    __shared__ float    redw[2][4];

    if (t < Nn) {
        inv_s[0][perms[(b0 * Pn + p) * Nn + t]] = t;
        valid_s[t] = ws[VOFFW + p * Nn + t];
    } else {
        inv_s[1][perms[(b1 * Pn + p) * Nn + (t - Nn)]] = t - Nn;
    }
    {
        const uint32_t* Bp = (const uint32_t*)ws + BOFF + p * Nn * 4;
        B_s[t]       = Bp[t];
        B_s[256 + t] = Bp[256 + t];
    }
    __syncthreads();

    int lane = t & 63;
    int wid  = t >> 6;
    int v0 = 2 * lane, v1 = v0 + 1;

    // loop-invariant per (batch, slot) coordinates
    int   j00 = inv_s[0][v0], j01 = inv_s[0][v1];
    int   j10 = inv_s[1][v0], j11 = inv_s[1][v1];
    float wv00 = valid_s[j00], wv01 = valid_s[j01];
    float wv10 = valid_s[j10], wv11 = valid_s[j11];
    int   a00 = j00 >> 5, sh00 = j00 & 31;
    int   a01 = j01 >> 5, sh01 = j01 & 31;
    int   a10 = j10 >> 5, sh10 = j10 & 31;
    int   a11 = j11 >> 5, sh11 = j11 & 31;

    const uint2* tab2 = (const uint2*)((const uint32_t*)ws + p * (Nn * Nn));
    float acc0 = 0.f, acc1 = 0.f;

#pragma unroll 4
    for (int it = 0; it < 32; ++it) {
        int u = it * 4 + wid;                       // row: wave-uniform
        int   si0  = inv_s[0][u];                   // broadcast LDS reads
        int   si1  = inv_s[1][u];
        float swu0 = valid_s[si0];
        float swu1 = valid_s[si1];
        uint2 hw   = tab2[u * (Nn / 2) + lane];     // coalesced 8B/lane
        float2 f0  = __half22float2(*(__half2*)&hw.x);  // x=logsig(-l), y=l  @ v0
        float2 f1  = __half22float2(*(__half2*)&hw.y);  //                    @ v1

        // batch 0
        {
            float tmp = wv00 * f0.x;
            tmp = fmaf(wv01, f1.x, tmp);
            acc0 = fmaf(swu0, tmp, acc0);
            uint32_t r0 = B_s[si0 * 4 + a00];
            uint32_t r1 = B_s[si0 * 4 + a01];
            acc0 += ((r0 >> sh00) & 1u) ? f0.y : 0.0f;
            acc0 += ((r1 >> sh01) & 1u) ? f1.y : 0.0f;
        }
        // batch 1
        {
            float tmp = wv10 * f0.x;
            tmp = fmaf(wv11, f1.x, tmp);
            acc1 = fmaf(swu1, tmp, acc1);
            uint32_t r0 = B_s[si1 * 4 + a10];
            uint32_t r1 = B_s[si1 * 4 + a11];
            acc1 += ((r0 >> sh10) & 1u) ? f0.y : 0.0f;
            acc1 += ((r1 >> sh11) & 1u) ? f1.y : 0.0f;
        }
    }

    // wave reduce both accumulators
#pragma unroll
    for (int s = 32; s > 0; s >>= 1) {
        acc0 += __shfl_down(acc0, s, 64);
        acc1 += __shfl_down(acc1, s, 64);
    }
    if (lane == 0) { redw[0][wid] = acc0; redw[1][wid] = acc1; }
    __syncthreads();
    if (t < 2) {
        float r = redw[t][0] + redw[t][1] + redw[t][2] + redw[t][3];
        rec[(b0 + t) * Pn + p] = r;
    }
}

// ---------------- K3: KL + RE = sum_b max_p rec ; out = mean(KL) - RE ----------------
__global__ void k_final(const float* __restrict__ mu,
                        const float* __restrict__ logstd,
                        const float* __restrict__ eps,
                        const float* __restrict__ ws,
                        float* __restrict__ out) {
    int t = threadIdx.x;   // 128 threads, one per b
    float kl = 0.f;
    for (int l = 0; l < Ln; ++l) {
        int   idx = t * Ln + l;
        float e = eps[idx], ls = logstd[idx];
        float z = mu[idx] + e * __expf(ls);
        kl += -0.5f * e * e - ls + 0.5f * z * z;   // 0.5*log(2pi) cancels
    }
    float m = -INFINITY;
    for (int p = 0; p < Pn; p++) m = fmaxf(m, ws[ROFF + t * Pn + p]);
    float contrib = kl * (1.0f / Bn) - m;
    __shared__ float red[128];
    red[t] = contrib;
    __syncthreads();
    for (int s = 64; s > 0; s >>= 1) {
        if (t < s) red[t] += red[t + s];
        __syncthreads();
    }
    if (t == 0) out[0] = red[0];
}

extern "C" void kernel_launch(void* const* d_in, const int* in_sizes, int n_in,
                              void* d_out, int out_size, void* d_ws, size_t ws_size,
                              hipStream_t stream) {
    const float* mu     = (const float*)d_in[0];
    const float* logstd = (const float*)d_in[1];
    const float* eps    = (const float*)d_in[2];
    const float* W      = (const float*)d_in[3];
    const int*   Adj    = (const int*)d_in[4];
    const int*   nm     = (const int*)d_in[5];
    const int*   perms  = (const int*)d_in[6];
    float* ws  = (float*)d_ws;
    float* out = (float*)d_out;

    hipLaunchKernelGGL(k_prep,  dim3(192 + Pn), dim3(256), 0, stream,
                       mu, logstd, eps, W, Adj, nm, ws);
    hipLaunchKernelGGL(k_main,  dim3(Pn * 64),  dim3(256), 0, stream,
                       perms, ws, ws + ROFF);
    hipLaunchKernelGGL(k_final, dim3(1),        dim3(128), 0, stream,
                       mu, logstd, eps, ws, out);
}